// Round 4
// baseline (869.886 us; speedup 1.0000x reference)
//
#include <hip/hip_runtime.h>
#include <hip/hip_bf16.h>
#include <cstdint>

constexpr int LSEQ  = 384;
constexpr int BATCH = 8;
constexpr int HID   = 512;
constexpr int NHEAD = 8;
constexpr int DKH   = 64;
constexpr int NLAY  = 4;
constexpr int BL    = BATCH * LSEQ;      // 3072 rows
constexpr int LL2   = LSEQ * LSEQ;       // 147456 pairs per batch
constexpr int BH    = BATCH * NHEAD;     // 64

typedef __bf16 bf16x8 __attribute__((ext_vector_type(8)));
typedef float  f32x4  __attribute__((ext_vector_type(4)));
typedef unsigned short ushort_t;

__device__ inline bf16x8 load_frag(const void* p) {
    uint4 u = *reinterpret_cast<const uint4*>(p);
    return __builtin_bit_cast(bf16x8, u);
}
__device__ inline bf16x8 zero_frag() {
    uint4 u = {0u, 0u, 0u, 0u};
    return __builtin_bit_cast(bf16x8, u);
}
__device__ inline f32x4 mfma16(bf16x8 a, bf16x8 b, f32x4 c) {
    return __builtin_amdgcn_mfma_f32_16x16x32_bf16(a, b, c, 0, 0, 0);
}
__device__ inline float b2f(__hip_bfloat16 v) { return __bfloat162float(v); }
__device__ inline ushort_t bfbits(float f) {
    __hip_bfloat16 b = __float2bfloat16(f);
    return *(ushort_t*)&b;
}

// ---------------------------------------------------------------------------
// Normalize mask storage -> uchar[3072]; also zero the fp32 output buffer
// (final LN accumulates into it with atomics).
__global__ __launch_bounds__(1024) void mask_norm_kernel(
    const unsigned char* __restrict__ raw, unsigned char* __restrict__ m,
    float* __restrict__ outz)
{
    __shared__ int fl;
    const int tid = threadIdx.x;
    if (tid == 0) fl = 0;
    __syncthreads();
    int f = 0;
    for (int i = tid; i < BL; i += 1024) {
        const unsigned char v = raw[i];
        if (v > 1) f |= 1;
        if (v && (i & 3)) f |= 2;
        if (v && ((i & 7) == 4)) f |= 4;
        if (v && ((i & 3) <= 1)) f |= 8;
    }
    if (f) atomicOr(&fl, f);
    for (int i = tid; i < BATCH * HID; i += 1024) outz[i] = 0.f;
    __syncthreads();
    const int ff = fl;
    int stride, off;
    if (ff & 1) { if (ff & 8) { stride = 2; off = 0; } else { stride = 4; off = 2; } }
    else if (ff & 2) { stride = 1; off = 0; }
    else if (ff & 4) { stride = 4; off = 0; }
    else             { stride = 8; off = 0; }
    for (int i = tid; i < BL; i += 1024)
        m[i] = raw[(size_t)i * stride + off] ? 1 : 0;
}

// ---------------------------------------------------------------------------
// Merged weight prep: blocks <4096 = QKV/O transpose+convert; rest = ref-MLP
// weights to MFMA B-layout. grid 4136 x 256.
__global__ __launch_bounds__(256) void wconv_refw_kernel(
    const float* __restrict__ Wq, const float* __restrict__ Wk,
    const float* __restrict__ Wv, const float* __restrict__ Wo,
    ushort_t* __restrict__ WTqkv, ushort_t* __restrict__ WTo,
    const float* __restrict__ Wr1, const float* __restrict__ Wr2,
    ushort_t* __restrict__ W1T, ushort_t* __restrict__ W2T)
{
    __shared__ float tile[32][33];
    if (blockIdx.x < 4096) {
        const int t = blockIdx.x;
        const int ml = t >> 8;            // mat*4 + layer
        const int rest = t & 255;
        const int mi = ml >> 2, l = ml & 3;
        const int tk = (rest & 15) * 32;
        const int tn = (rest >> 4) * 32;
        const float* W = (mi == 0) ? Wq : (mi == 1) ? Wk : (mi == 2) ? Wv : Wo;
        const float* src = W + (size_t)l * HID * HID;
        const int c = threadIdx.x & 31, r = threadIdx.x >> 5;
        for (int rr = r; rr < 32; rr += 8)
            tile[rr][c] = src[(size_t)(tk + rr) * HID + tn + c];
        __syncthreads();
        ushort_t* dst = (mi < 3)
            ? WTqkv + ((size_t)l * 1536 + mi * 512) * HID
            : WTo   + (size_t)l * HID * HID;
        for (int rr = r; rr < 32; rr += 8)
            dst[(size_t)(tn + rr) * HID + tk + c] = bfbits(tile[c][rr]);
    } else {
        const int tid = (blockIdx.x - 4096) * 256 + threadIdx.x;
        if (tid < 4 * 32 * 64) {
            const int l = tid >> 11, rem = tid & 2047;
            const int n = rem >> 6, k = rem & 63;
            W1T[tid] = (k < 53) ? bfbits(Wr1[(l * 53 + k) * 32 + n]) : (ushort_t)0;
        } else if (tid < 4 * 32 * 64 + 4 * 16 * 32) {
            const int t2 = tid - 8192;
            const int l = t2 >> 9, rem = t2 & 511;
            const int n = rem >> 5, k = rem & 31;
            W2T[t2] = (n < 8) ? bfbits(Wr2[(l * 32 + k) * 8 + n]) : (ushort_t)0;
        }
    }
}

// ---------------------------------------------------------------------------
// Merged: blocks <4608 = refCov MLP (all 4 layers); rest = pack h = x*mask.
// grid 10752 x 256.
__global__ __launch_bounds__(256) void refmlp_pack_kernel(
    const float* __restrict__ refCov,
    const ushort_t* __restrict__ W1T, const float* __restrict__ br1,
    const ushort_t* __restrict__ W2T, const float* __restrict__ br2,
    __hip_bfloat16* __restrict__ refL,
    const float* __restrict__ x, const unsigned char* __restrict__ mask,
    float* __restrict__ h, __hip_bfloat16* __restrict__ hb)
{
    __shared__ ushort_t smem[256 * 56];   // 28672 B: Atile, later C1 overlay

    if (blockIdx.x >= 4608) {
        const int idx = (blockIdx.x - 4608) * 256 + threadIdx.x;
        const int row = idx >> 9;
        const float v = mask[row] ? x[idx] : 0.f;
        h[idx] = v;
        hb[idx] = __float2bfloat16(v);
        return;
    }

    const int tid = threadIdx.x;
    const int w = tid >> 6, lane = tid & 63;
    const int lr = lane & 15, quad = lane >> 4;
    const size_t p0 = (size_t)blockIdx.x * 256;
    const int b = (int)(p0 / LL2);
    const int rem0 = (int)(p0 - (size_t)b * LL2);

    const float4* src4 = reinterpret_cast<const float4*>(refCov + p0 * 53);
    for (int f = tid; f < 3392; f += 256) {
        float4 v = src4[f];
        const int e = f * 4;
        #pragma unroll
        for (int k = 0; k < 4; ++k) {
            const int g = e + k;
            const int row = g / 53;
            const int col = g - row * 53;
            smem[row * 56 + col] = bfbits(((const float*)&v)[k]);
        }
    }
    smem[tid * 56 + 53] = 0;
    smem[tid * 56 + 54] = 0;
    smem[tid * 56 + 55] = 0;
    __syncthreads();

    bf16x8 afr[4][2];
    #pragma unroll
    for (int mi = 0; mi < 4; ++mi) {
        const ushort_t* rp = smem + (w * 64 + mi * 16 + lr) * 56;
        afr[mi][0] = load_frag(rp + quad * 8);
        afr[mi][1] = (quad < 3) ? load_frag(rp + 32 + quad * 8) : zero_frag();
    }
    __syncthreads();

    ushort_t* C1w = smem + w * 2560;   // per-wave [64][40] bf16

    #pragma unroll
    for (int l = 0; l < NLAY; ++l) {
        const float bias0 = br1[l * 32 + lr];
        const float bias1 = br1[l * 32 + 16 + lr];
        const float bias2 = br2[l * 8 + (lr & 7)];
        bf16x8 w1f[2][2];
        #pragma unroll
        for (int ni = 0; ni < 2; ++ni)
            #pragma unroll
            for (int ks = 0; ks < 2; ++ks)
                w1f[ni][ks] = load_frag(W1T + ((l * 32 + ni * 16 + lr) * 64) + ks * 32 + quad * 8);
        bf16x8 w2f = load_frag(W2T + (l * 16 + lr) * 32 + quad * 8);

        f32x4 acc[4][2];
        #pragma unroll
        for (int mi = 0; mi < 4; ++mi) {
            acc[mi][0] = (f32x4){bias0, bias0, bias0, bias0};
            acc[mi][1] = (f32x4){bias1, bias1, bias1, bias1};
        }
        #pragma unroll
        for (int mi = 0; mi < 4; ++mi) {
            acc[mi][0] = mfma16(afr[mi][0], w1f[0][0], acc[mi][0]);
            acc[mi][0] = mfma16(afr[mi][1], w1f[0][1], acc[mi][0]);
            acc[mi][1] = mfma16(afr[mi][0], w1f[1][0], acc[mi][1]);
            acc[mi][1] = mfma16(afr[mi][1], w1f[1][1], acc[mi][1]);
        }
        #pragma unroll
        for (int mi = 0; mi < 4; ++mi)
            #pragma unroll
            for (int ni = 0; ni < 2; ++ni)
                #pragma unroll
                for (int r = 0; r < 4; ++r)
                    C1w[(mi * 16 + quad * 4 + r) * 40 + ni * 16 + lr] =
                        bfbits(fmaxf(acc[mi][ni][r], 0.f));

        #pragma unroll
        for (int mi = 0; mi < 4; ++mi) {
            bf16x8 a2 = load_frag(C1w + (mi * 16 + lr) * 40 + quad * 8);
            f32x4 a = (f32x4){bias2, bias2, bias2, bias2};
            a = mfma16(a2, w2f, a);
            if (lr < 8) {
                uint2 pk;
                pk.x = (unsigned)bfbits(a[0]) | ((unsigned)bfbits(a[1]) << 16);
                pk.y = (unsigned)bfbits(a[2]) | ((unsigned)bfbits(a[3]) << 16);
                const size_t plane = ((size_t)(l * 8 + b) * 8 + lr) * LL2;
                *reinterpret_cast<uint2*>((ushort_t*)refL + plane + rem0 +
                                          w * 64 + mi * 16 + quad * 4) = pk;
            }
        }
    }
}

// ---------------------------------------------------------------------------
// Fused QKV GEMM: [3072,512] @ WTqkv^T[1536] -> q/k/vT. grid 1152 x 256.
__global__ __launch_bounds__(256) void gemm_qkv_kernel(
    const __hip_bfloat16* __restrict__ A,
    const __hip_bfloat16* __restrict__ BT,
    const float* __restrict__ bq, const float* __restrict__ bk,
    const float* __restrict__ bv,
    __hip_bfloat16* __restrict__ q, __hip_bfloat16* __restrict__ kk,
    __hip_bfloat16* __restrict__ vT)
{
    const int bm = blockIdx.x % (BL / 64);
    const int bn = blockIdx.x / (BL / 64);     // 0..23
    const int wv = threadIdx.x >> 6;
    const int lane = threadIdx.x & 63;
    const int lr = lane & 15, quad = lane >> 4;
    const int m0 = bm * 64 + (wv & 1) * 32;
    const int n0g = bn * 64 + (wv >> 1) * 32;  // global n' in [0,1536)
    f32x4 acc[2][2];
    #pragma unroll
    for (int i = 0; i < 2; ++i)
        #pragma unroll
        for (int j = 0; j < 2; ++j) acc[i][j] = (f32x4){0.f, 0.f, 0.f, 0.f};
    const __hip_bfloat16* a0p = A + (size_t)(m0 + lr) * HID;
    const __hip_bfloat16* a1p = A + (size_t)(m0 + 16 + lr) * HID;
    const __hip_bfloat16* b0p = BT + (size_t)(n0g + lr) * HID;
    const __hip_bfloat16* b1p = BT + (size_t)(n0g + 16 + lr) * HID;
    #pragma unroll 4
    for (int k0 = 0; k0 < HID; k0 += 32) {
        const int ka = k0 + quad * 8;
        bf16x8 a0 = load_frag(a0p + ka);
        bf16x8 a1 = load_frag(a1p + ka);
        bf16x8 b0 = load_frag(b0p + ka);
        bf16x8 b1 = load_frag(b1p + ka);
        acc[0][0] = mfma16(a0, b0, acc[0][0]);
        acc[0][1] = mfma16(a0, b1, acc[0][1]);
        acc[1][0] = mfma16(a1, b0, acc[1][0]);
        acc[1][1] = mfma16(a1, b1, acc[1][1]);
    }
    const int mat = n0g >> 9;
    const float* bias = (mat == 0) ? bq : (mat == 1) ? bk : bv;
    const float scale = (mat == 0) ? 0.125f : 1.0f;
    __hip_bfloat16* outp = (mat == 0) ? q : (mat == 1) ? kk : vT;
    #pragma unroll
    for (int mi = 0; mi < 2; ++mi)
        #pragma unroll
        for (int ni = 0; ni < 2; ++ni)
            #pragma unroll
            for (int r = 0; r < 4; ++r) {
                const int m = m0 + mi * 16 + quad * 4 + r;
                const int ng = n0g + ni * 16 + lr;
                const int n = ng & 511;
                float v = (acc[mi][ni][r] + bias[n]) * scale;
                const int bb = m / LSEQ, ii = m % LSEQ;
                const int hh = n >> 6, d = n & 63;
                if (mat == 2)
                    outp[((size_t)(bb * NHEAD + hh) * DKH + d) * LSEQ + ii] = __float2bfloat16(v);
                else
                    outp[((size_t)(bb * NHEAD + hh) * LSEQ + ii) * DKH + d] = __float2bfloat16(v);
            }
}

// ---------------------------------------------------------------------------
// O-projection: proj[3072,512] = AO @ WTo^T + bo (fp32 out). grid 384 x 256.
__global__ __launch_bounds__(256) void gemm_oproj_kernel(
    const __hip_bfloat16* __restrict__ A,
    const __hip_bfloat16* __restrict__ BT,
    const float* __restrict__ bias,
    float* __restrict__ outf)
{
    const int bm = blockIdx.x % (BL / 64);
    const int bn = blockIdx.x / (BL / 64);
    const int wv = threadIdx.x >> 6;
    const int lane = threadIdx.x & 63;
    const int lr = lane & 15, quad = lane >> 4;
    const int m0 = bm * 64 + (wv & 1) * 32;
    const int n0 = bn * 64 + (wv >> 1) * 32;
    f32x4 acc[2][2];
    #pragma unroll
    for (int i = 0; i < 2; ++i)
        #pragma unroll
        for (int j = 0; j < 2; ++j) acc[i][j] = (f32x4){0.f, 0.f, 0.f, 0.f};
    const __hip_bfloat16* a0p = A + (size_t)(m0 + lr) * HID;
    const __hip_bfloat16* a1p = A + (size_t)(m0 + 16 + lr) * HID;
    const __hip_bfloat16* b0p = BT + (size_t)(n0 + lr) * HID;
    const __hip_bfloat16* b1p = BT + (size_t)(n0 + 16 + lr) * HID;
    #pragma unroll 4
    for (int k0 = 0; k0 < HID; k0 += 32) {
        const int ka = k0 + quad * 8;
        bf16x8 a0 = load_frag(a0p + ka);
        bf16x8 a1 = load_frag(a1p + ka);
        bf16x8 b0 = load_frag(b0p + ka);
        bf16x8 b1 = load_frag(b1p + ka);
        acc[0][0] = mfma16(a0, b0, acc[0][0]);
        acc[0][1] = mfma16(a0, b1, acc[0][1]);
        acc[1][0] = mfma16(a1, b0, acc[1][0]);
        acc[1][1] = mfma16(a1, b1, acc[1][1]);
    }
    #pragma unroll
    for (int mi = 0; mi < 2; ++mi)
        #pragma unroll
        for (int ni = 0; ni < 2; ++ni)
            #pragma unroll
            for (int r = 0; r < 4; ++r) {
                const int m = m0 + mi * 16 + quad * 4 + r;
                const int n = n0 + ni * 16 + lr;
                outf[(size_t)m * HID + n] = acc[mi][ni][r] + bias[n];
            }
}

// ---------------------------------------------------------------------------
// Fused attention (4-wave, round-2 proven): S=QK^T (regs) -> dual masked
// softmax -> P (LDS) -> PV -> AO. grid 768 x 256.
// Wave w: s=w&1 row-strip (16 rows), h2=w>>1 col-half (192 cols).
__global__ __launch_bounds__(256) void attn_fused_kernel(
    const __hip_bfloat16* __restrict__ Q,    // [bh][i][d]
    const __hip_bfloat16* __restrict__ Km,   // [bh][j][d]
    const __hip_bfloat16* __restrict__ VT,   // [bh][d][j]
    const __hip_bfloat16* __restrict__ refl, // + l*BH*LL2, [bh][i][j]
    const unsigned char* __restrict__ mask,
    __hip_bfloat16* __restrict__ AO)         // [b*384+i][h*64+d]
{
    __shared__ __align__(16) ushort_t Pl[32 * 392];   // P tile, padded rows
    __shared__ float redm_s[2][2][16], redm_r[2][2][16];
    __shared__ float reds_s[2][2][16], reds_r[2][2][16];

    const int bh = blockIdx.x / 12;
    const int i0 = (blockIdx.x % 12) * 32;
    const int b  = bh >> 3, hh = bh & 7;
    const int w = threadIdx.x >> 6, lane = threadIdx.x & 63;
    const int s = w & 1, h2 = w >> 1;
    const int lr = lane & 15, quad = lane >> 4;

    const __hip_bfloat16* qb = Q  + (size_t)bh * LSEQ * DKH;
    const __hip_bfloat16* kb = Km + (size_t)bh * LSEQ * DKH;
    const unsigned char* mrow = mask + b * LSEQ;

    // ---- S strip: rows [i0+s*16, +16), cols [h2*192, +192) ----
    f32x4 acc[12];
    #pragma unroll
    for (int nt = 0; nt < 12; ++nt) acc[nt] = (f32x4){0.f, 0.f, 0.f, 0.f};
    #pragma unroll
    for (int k0 = 0; k0 < DKH; k0 += 32) {
        const int ka = k0 + quad * 8;
        bf16x8 a = load_frag(qb + (size_t)(i0 + s * 16 + lr) * DKH + ka);
        #pragma unroll
        for (int nt = 0; nt < 12; ++nt) {
            bf16x8 bf = load_frag(kb + (size_t)(h2 * 192 + nt * 16 + lr) * DKH + ka);
            acc[nt] = mfma16(a, bf, acc[nt]);
        }
    }

    // ---- column masks + ref values (same lane mapping as acc) ----
    bool vm[12];
    #pragma unroll
    for (int nt = 0; nt < 12; ++nt)
        vm[nt] = mrow[h2 * 192 + nt * 16 + lr] != 0;

    const __hip_bfloat16* rbase = refl + (size_t)bh * LL2 +
                                  (size_t)(i0 + s * 16) * LSEQ + h2 * 192;
    float rv[12][4];
    #pragma unroll
    for (int nt = 0; nt < 12; ++nt)
        #pragma unroll
        for (int r = 0; r < 4; ++r)
            rv[nt][r] = b2f(rbase[(size_t)(quad * 4 + r) * LSEQ + nt * 16 + lr]);

    // ---- masked max (per row: in-reg over nt, shfl over lr, LDS over halves) ----
    float ms[4], mr2[4];
    #pragma unroll
    for (int r = 0; r < 4; ++r) { ms[r] = -1e30f; mr2[r] = -1e30f; }
    #pragma unroll
    for (int nt = 0; nt < 12; ++nt)
        #pragma unroll
        for (int r = 0; r < 4; ++r) {
            acc[nt][r] = vm[nt] ? acc[nt][r] : -1e30f;
            rv[nt][r]  = vm[nt] ? rv[nt][r]  : -1e30f;
            ms[r]  = fmaxf(ms[r],  acc[nt][r]);
            mr2[r] = fmaxf(mr2[r], rv[nt][r]);
        }
    #pragma unroll
    for (int off = 8; off > 0; off >>= 1)
        #pragma unroll
        for (int r = 0; r < 4; ++r) {
            ms[r]  = fmaxf(ms[r],  __shfl_xor(ms[r],  off));
            mr2[r] = fmaxf(mr2[r], __shfl_xor(mr2[r], off));
        }
    if (lr == 0)
        #pragma unroll
        for (int r = 0; r < 4; ++r) {
            redm_s[s][h2][quad * 4 + r] = ms[r];
            redm_r[s][h2][quad * 4 + r] = mr2[r];
        }
    __syncthreads();
    #pragma unroll
    for (int r = 0; r < 4; ++r) {
        ms[r]  = fmaxf(redm_s[s][0][quad * 4 + r], redm_s[s][1][quad * 4 + r]);
        mr2[r] = fmaxf(redm_r[s][0][quad * 4 + r], redm_r[s][1][quad * 4 + r]);
    }

    // ---- exp + sum (es/er overwrite acc/rv) ----
    float Ss[4] = {0.f, 0.f, 0.f, 0.f}, Sr[4] = {0.f, 0.f, 0.f, 0.f};
    #pragma unroll
    for (int nt = 0; nt < 12; ++nt)
        #pragma unroll
        for (int r = 0; r < 4; ++r) {
            acc[nt][r] = __expf(acc[nt][r] - ms[r]);  Ss[r] += acc[nt][r];
            rv[nt][r]  = __expf(rv[nt][r]  - mr2[r]); Sr[r] += rv[nt][r];
        }
    #pragma unroll
    for (int off = 8; off > 0; off >>= 1)
        #pragma unroll
        for (int r = 0; r < 4; ++r) {
            Ss[r] += __shfl_xor(Ss[r], off);
            Sr[r] += __shfl_xor(Sr[r], off);
        }
    if (lr == 0)
        #pragma unroll
        for (int r = 0; r < 4; ++r) {
            reds_s[s][h2][quad * 4 + r] = Ss[r];
            reds_r[s][h2][quad * 4 + r] = Sr[r];
        }
    __syncthreads();

    // ---- combine -> P (bf16, LDS) ----
    float cs[4], cr[4], rm[4];
    #pragma unroll
    for (int r = 0; r < 4; ++r) {
        const float SsF = reds_s[s][0][quad * 4 + r] + reds_s[s][1][quad * 4 + r];
        const float SrF = reds_r[s][0][quad * 4 + r] + reds_r[s][1][quad * 4 + r];
        cs[r] = 0.5f / SsF;
        cr[r] = 0.5f / SrF;
        rm[r] = mrow[i0 + s * 16 + quad * 4 + r] ? 1.f : 0.f;
    }
    #pragma unroll
    for (int nt = 0; nt < 12; ++nt)
        #pragma unroll
        for (int r = 0; r < 4; ++r)
            Pl[(s * 16 + quad * 4 + r) * 392 + h2 * 192 + nt * 16 + lr] =
                bfbits((acc[nt][r] * cs[r] + rv[nt][r] * cr[r]) * rm[r]);
    __syncthreads();

    // ---- PV: out strip = rows [s*16,+16) x d [h2*32,+32) ----
    const __hip_bfloat16* vb = VT + (size_t)bh * DKH * LSEQ;
    f32x4 oa[2];
    oa[0] = (f32x4){0.f, 0.f, 0.f, 0.f};
    oa[1] = (f32x4){0.f, 0.f, 0.f, 0.f};
    #pragma unroll 4
    for (int k0 = 0; k0 < LSEQ; k0 += 32) {
        const int ka = k0 + quad * 8;
        bf16x8 a = load_frag(Pl + (s * 16 + lr) * 392 + ka);
        #pragma unroll
        for (int dt = 0; dt < 2; ++dt) {
            bf16x8 bf = load_frag(vb + (size_t)(h2 * 32 + dt * 16 + lr) * LSEQ + ka);
            oa[dt] = mfma16(a, bf, oa[dt]);
        }
    }
    #pragma unroll
    for (int dt = 0; dt < 2; ++dt)
        #pragma unroll
        for (int r = 0; r < 4; ++r)
            AO[(size_t)(b * LSEQ + i0 + s * 16 + quad * 4 + r) * HID +
               hh * DKH + h2 * 32 + dt * 16 + lr] = __float2bfloat16(oa[dt][r]);
}

// ---------------------------------------------------------------------------
// LayerNorm, wave-per-row (no barriers): y = LN(resid+proj); writes fp32+bf16.
// grid 768 x 256 (4 rows/block).
__global__ __launch_bounds__(256) void ln4_kernel(
    const float* __restrict__ resid, const float* __restrict__ proj,
    const float* __restrict__ g, const float* __restrict__ beta,
    float* __restrict__ outf, __hip_bfloat16* __restrict__ outb)
{
    const int w = threadIdx.x >> 6, lane = threadIdx.x & 63;
    const int row = blockIdx.x * 4 + w;
    const size_t base = (size_t)row * HID + lane * 8;
    float4 a0 = *reinterpret_cast<const float4*>(resid + base);
    float4 a1 = *reinterpret_cast<const float4*>(resid + base + 4);
    const float4 p0 = *reinterpret_cast<const float4*>(proj + base);
    const float4 p1 = *reinterpret_cast<const float4*>(proj + base + 4);
    a0.x += p0.x; a0.y += p0.y; a0.z += p0.z; a0.w += p0.w;
    a1.x += p1.x; a1.y += p1.y; a1.z += p1.z; a1.w += p1.w;
    float xs[8] = {a0.x, a0.y, a0.z, a0.w, a1.x, a1.y, a1.z, a1.w};
    float sum = 0.f, sq = 0.f;
    #pragma unroll
    for (int j = 0; j < 8; ++j) { sum += xs[j]; sq += xs[j] * xs[j]; }
    #pragma unroll
    for (int off = 32; off > 0; off >>= 1) {
        sum += __shfl_xor(sum, off);
        sq  += __shfl_xor(sq, off);
    }
    const float mu = sum * (1.f / HID);
    const float var = sq * (1.f / HID) - mu * mu;
    const float rstd = rsqrtf(var + 1e-5f);
    const float4 g0 = *reinterpret_cast<const float4*>(g + lane * 8);
    const float4 g1 = *reinterpret_cast<const float4*>(g + lane * 8 + 4);
    const float4 b0 = *reinterpret_cast<const float4*>(beta + lane * 8);
    const float4 b1 = *reinterpret_cast<const float4*>(beta + lane * 8 + 4);
    const float gg[8] = {g0.x, g0.y, g0.z, g0.w, g1.x, g1.y, g1.z, g1.w};
    const float bb[8] = {b0.x, b0.y, b0.z, b0.w, b1.x, b1.y, b1.z, b1.w};
    float y[8];
    #pragma unroll
    for (int j = 0; j < 8; ++j) y[j] = (xs[j] - mu) * rstd * gg[j] + bb[j];
    float4 o0 = {y[0], y[1], y[2], y[3]}, o1 = {y[4], y[5], y[6], y[7]};
    *reinterpret_cast<float4*>(outf + base) = o0;
    *reinterpret_cast<float4*>(outf + base + 4) = o1;
    uint4 pb;
    pb.x = (unsigned)bfbits(y[0]) | ((unsigned)bfbits(y[1]) << 16);
    pb.y = (unsigned)bfbits(y[2]) | ((unsigned)bfbits(y[3]) << 16);
    pb.z = (unsigned)bfbits(y[4]) | ((unsigned)bfbits(y[5]) << 16);
    pb.w = (unsigned)bfbits(y[6]) | ((unsigned)bfbits(y[7]) << 16);
    *reinterpret_cast<uint4*>(outb + base) = pb;
}

// ---------------------------------------------------------------------------
// Final LN + masked sequence-sum fused: atomicAdd rows into out[b][c].
// grid 768 x 256 (4 rows/block). out pre-zeroed by mask_norm_kernel.
__global__ __launch_bounds__(256) void ln_final_kernel(
    const float* __restrict__ resid, const float* __restrict__ g,
    const float* __restrict__ beta, const unsigned char* __restrict__ mask,
    float* __restrict__ out)
{
    const int w = threadIdx.x >> 6, lane = threadIdx.x & 63;
    const int row = blockIdx.x * 4 + w;
    if (!mask[row]) return;
    const int b = row / LSEQ;
    const size_t base = (size_t)row * HID + lane * 8;
    const float4 a0 = *reinterpret_cast<const float4*>(resid + base);
    const float4 a1 = *reinterpret_cast<const float4*>(resid + base + 4);
    float xs[8] = {a0.x, a0.y, a0.z, a0.w, a1.x, a1.y, a1.z, a1.w};
    float sum = 0.f, sq = 0.f;
    #pragma unroll
    for (int j = 0; j < 8; ++j) { sum += xs[j]; sq += xs[j] * xs[j]; }
    #pragma unroll
    for (int off = 32; off > 0; off >>= 1) {
        sum += __shfl_xor(sum, off);
        sq  += __shfl_xor(sq, off);
    }
    const float mu = sum * (1.f / HID);
    const float var = sq * (1.f / HID) - mu * mu;
    const float rstd = rsqrtf(var + 1e-5f);
    const float4 g0 = *reinterpret_cast<const float4*>(g + lane * 8);
    const float4 g1 = *reinterpret_cast<const float4*>(g + lane * 8 + 4);
    const float4 b0 = *reinterpret_cast<const float4*>(beta + lane * 8);
    const float4 b1 = *reinterpret_cast<const float4*>(beta + lane * 8 + 4);
    const float gg[8] = {g0.x, g0.y, g0.z, g0.w, g1.x, g1.y, g1.z, g1.w};
    const float bb[8] = {b0.x, b0.y, b0.z, b0.w, b1.x, b1.y, b1.z, b1.w};
    float* orow = out + (size_t)b * HID + lane * 8;
    #pragma unroll
    for (int j = 0; j < 8; ++j)
        atomicAdd(orow + j, (xs[j] - mu) * rstd * gg[j] + bb[j]);
}

// ---------------------------------------------------------------------------
extern "C" void kernel_launch(void* const* d_in, const int* in_sizes, int n_in,
                              void* d_out, int out_size, void* d_ws, size_t ws_size,
                              hipStream_t stream)
{
    const float* x   = (const float*)d_in[0];
    const unsigned char* mraw = (const unsigned char*)d_in[1];
    const float* refCov = (const float*)d_in[2];
    const float* Wq = (const float*)d_in[3];
    const float* bq = (const float*)d_in[4];
    const float* Wk = (const float*)d_in[5];
    const float* bk = (const float*)d_in[6];
    const float* Wv = (const float*)d_in[7];
    const float* bv = (const float*)d_in[8];
    const float* Wo = (const float*)d_in[9];
    const float* bo = (const float*)d_in[10];
    const float* Wr1 = (const float*)d_in[11];
    const float* br1 = (const float*)d_in[12];
    const float* Wr2 = (const float*)d_in[13];
    const float* br2 = (const float*)d_in[14];
    const float* ln_g = (const float*)d_in[15];
    const float* ln_b = (const float*)d_in[16];
    const float* fn_g = (const float*)d_in[17];
    const float* fn_b = (const float*)d_in[18];
    float* outp = (float*)d_out;

    char* ws = (char*)d_ws;
    size_t off = 0;
    auto alloc = [&](size_t bytes) -> char* {
        char* p = ws + off;
        off += (bytes + 255) & ~(size_t)255;
        return p;
    };
    __hip_bfloat16* refL  = (__hip_bfloat16*)alloc((size_t)NLAY * BH * LL2 * 2);
    float*          h     = (float*)alloc((size_t)BL * HID * 4);
    __hip_bfloat16* hb    = (__hip_bfloat16*)alloc((size_t)BL * HID * 2);
    __hip_bfloat16* q     = (__hip_bfloat16*)alloc((size_t)BH * LSEQ * DKH * 2);
    __hip_bfloat16* kk    = (__hip_bfloat16*)alloc((size_t)BH * LSEQ * DKH * 2);
    __hip_bfloat16* vT    = (__hip_bfloat16*)alloc((size_t)BH * DKH * LSEQ * 2);
    __hip_bfloat16* AO    = (__hip_bfloat16*)alloc((size_t)BL * HID * 2);
    float*          proj  = (float*)alloc((size_t)BL * HID * 4);
    ushort_t*       WTqkv = (ushort_t*)alloc((size_t)NLAY * 1536 * HID * 2);
    ushort_t*       WTo   = (ushort_t*)alloc((size_t)NLAY * HID * HID * 2);
    ushort_t*       W1T   = (ushort_t*)alloc((size_t)4 * 32 * 64 * 2);
    ushort_t*       W2T   = (ushort_t*)alloc((size_t)4 * 16 * 32 * 2);
    unsigned char*  msk   = (unsigned char*)alloc(BL);

    mask_norm_kernel<<<1, 1024, 0, stream>>>(mraw, msk, outp);
    wconv_refw_kernel<<<4136, 256, 0, stream>>>(Wq, Wk, Wv, Wo, WTqkv, WTo,
                                                Wr1, Wr2, W1T, W2T);
    refmlp_pack_kernel<<<10752, 256, 0, stream>>>(refCov, W1T, br1, W2T, br2, refL,
                                                  x, msk, h, hb);

    for (int l = 0; l < NLAY; ++l) {
        const __hip_bfloat16* WTl = (const __hip_bfloat16*)(WTqkv + (size_t)l * 1536 * HID);
        const __hip_bfloat16* WTol = (const __hip_bfloat16*)(WTo + (size_t)l * HID * HID);
        gemm_qkv_kernel<<<1152, 256, 0, stream>>>(hb, WTl, bq + l * HID, bk + l * HID,
                                                  bv + l * HID, q, kk, vT);
        attn_fused_kernel<<<768, 256, 0, stream>>>(q, kk, vT,
                                                   refL + (size_t)l * BH * LL2, msk, AO);
        gemm_oproj_kernel<<<384, 256, 0, stream>>>(AO, WTol, bo + l * HID, proj);
        ln4_kernel<<<768, 256, 0, stream>>>(h, proj, ln_g + l * HID, ln_b + l * HID,
                                            h, hb);
    }
    ln_final_kernel<<<768, 256, 0, stream>>>(h, fn_g, fn_b, msk, outp);
}

// Round 5
// 829.989 us; speedup vs baseline: 1.0481x; 1.0481x over previous
//
#include <hip/hip_runtime.h>
#include <hip/hip_bf16.h>
#include <cstdint>

constexpr int LSEQ  = 384;
constexpr int BATCH = 8;
constexpr int HID   = 512;
constexpr int NHEAD = 8;
constexpr int DKH   = 64;
constexpr int NLAY  = 4;
constexpr int BL    = BATCH * LSEQ;      // 3072 rows
constexpr int LL2   = LSEQ * LSEQ;       // 147456 pairs per batch
constexpr int BH    = BATCH * NHEAD;     // 64

typedef __bf16 bf16x8 __attribute__((ext_vector_type(8)));
typedef float  f32x4  __attribute__((ext_vector_type(4)));
typedef unsigned short ushort_t;

__device__ inline bf16x8 load_frag(const void* p) {
    uint4 u = *reinterpret_cast<const uint4*>(p);
    return __builtin_bit_cast(bf16x8, u);
}
__device__ inline bf16x8 zero_frag() {
    uint4 u = {0u, 0u, 0u, 0u};
    return __builtin_bit_cast(bf16x8, u);
}
__device__ inline f32x4 mfma16(bf16x8 a, bf16x8 b, f32x4 c) {
    return __builtin_amdgcn_mfma_f32_16x16x32_bf16(a, b, c, 0, 0, 0);
}
__device__ inline float b2f(__hip_bfloat16 v) { return __bfloat162float(v); }
__device__ inline ushort_t bfbits(float f) {
    __hip_bfloat16 b = __float2bfloat16(f);
    return *(ushort_t*)&b;
}

// ---------------------------------------------------------------------------
// Normalize mask storage (u8 / i32 / i64 / bf16 / f32 bools) -> uchar[3072].
__global__ __launch_bounds__(1024) void mask_norm_kernel(
    const unsigned char* __restrict__ raw, unsigned char* __restrict__ m)
{
    __shared__ int fl;
    const int tid = threadIdx.x;
    if (tid == 0) fl = 0;
    __syncthreads();
    int f = 0;
    for (int i = tid; i < BL; i += 1024) {
        const unsigned char v = raw[i];
        if (v > 1) f |= 1;
        if (v && (i & 3)) f |= 2;
        if (v && ((i & 7) == 4)) f |= 4;
        if (v && ((i & 3) <= 1)) f |= 8;
    }
    if (f) atomicOr(&fl, f);
    __syncthreads();
    const int ff = fl;
    int stride, off;
    if (ff & 1) { if (ff & 8) { stride = 2; off = 0; } else { stride = 4; off = 2; } }
    else if (ff & 2) { stride = 1; off = 0; }
    else if (ff & 4) { stride = 4; off = 0; }
    else             { stride = 8; off = 0; }
    for (int i = tid; i < BL; i += 1024)
        m[i] = raw[(size_t)i * stride + off] ? 1 : 0;
}

// ---------------------------------------------------------------------------
// Weight convert+transpose: fp32 -> bf16, MFMA B-layout.
__global__ __launch_bounds__(256) void wconv_kernel(
    const float* __restrict__ Wq, const float* __restrict__ Wk,
    const float* __restrict__ Wv, const float* __restrict__ Wo,
    ushort_t* __restrict__ WTqkv, ushort_t* __restrict__ WTo)
{
    __shared__ float tile[32][33];
    const int t = blockIdx.x;
    const int ml = t >> 8;            // mat*4 + layer
    const int rest = t & 255;
    const int mi = ml >> 2, l = ml & 3;
    const int tk = (rest & 15) * 32;
    const int tn = (rest >> 4) * 32;
    const float* W = (mi == 0) ? Wq : (mi == 1) ? Wk : (mi == 2) ? Wv : Wo;
    const float* src = W + (size_t)l * HID * HID;
    const int c = threadIdx.x & 31, r = threadIdx.x >> 5;
    for (int rr = r; rr < 32; rr += 8)
        tile[rr][c] = src[(size_t)(tk + rr) * HID + tn + c];
    __syncthreads();
    ushort_t* dst = (mi < 3)
        ? WTqkv + ((size_t)l * 1536 + mi * 512) * HID
        : WTo   + (size_t)l * HID * HID;
    for (int rr = r; rr < 32; rr += 8)
        dst[(size_t)(tn + rr) * HID + tk + c] = bfbits(tile[c][rr]);
}

// ---------------------------------------------------------------------------
// refCov-MLP weights -> bf16 MFMA B-layout in global.
__global__ __launch_bounds__(256) void refw_kernel(
    const float* __restrict__ Wr1, const float* __restrict__ Wr2,
    ushort_t* __restrict__ W1T, ushort_t* __restrict__ W2T)
{
    const int tid = blockIdx.x * 256 + threadIdx.x;
    if (tid < 4 * 32 * 64) {
        const int l = tid >> 11, rem = tid & 2047;
        const int n = rem >> 6, k = rem & 63;
        W1T[tid] = (k < 53) ? bfbits(Wr1[(l * 53 + k) * 32 + n]) : (ushort_t)0;
    } else if (tid < 4 * 32 * 64 + 4 * 16 * 32) {
        const int t2 = tid - 8192;
        const int l = t2 >> 9, rem = t2 & 511;
        const int n = rem >> 5, k = rem & 31;
        W2T[t2] = (n < 8) ? bfbits(Wr2[(l * 32 + k) * 8 + n]) : (ushort_t)0;
    }
}

// ---------------------------------------------------------------------------
// pack: h = x * mask (fp32 + bf16 copies). grid 6144 x 256
__global__ __launch_bounds__(256) void pack_kernel(
    const float* __restrict__ x, const unsigned char* __restrict__ mask,
    float* __restrict__ h, __hip_bfloat16* __restrict__ hb)
{
    const int idx = blockIdx.x * 256 + threadIdx.x;
    const int row = idx >> 9;
    const float v = mask[row] ? x[idx] : 0.f;
    h[idx] = v;
    hb[idx] = __float2bfloat16(v);
}

// ---------------------------------------------------------------------------
// refCov MLP: 256 pairs/block, A-frags register-resident. grid 4608 x 256.
__global__ __launch_bounds__(256) void refmlp_kernel(
    const float* __restrict__ refCov,
    const ushort_t* __restrict__ W1T, const float* __restrict__ br1,
    const ushort_t* __restrict__ W2T, const float* __restrict__ br2,
    __hip_bfloat16* __restrict__ refL)
{
    __shared__ ushort_t smem[256 * 56];   // 28672 B: Atile, later C1 overlay

    const int tid = threadIdx.x;
    const int w = tid >> 6, lane = tid & 63;
    const int lr = lane & 15, quad = lane >> 4;
    const size_t p0 = (size_t)blockIdx.x * 256;
    const int b = (int)(p0 / LL2);
    const int rem0 = (int)(p0 - (size_t)b * LL2);

    const float4* src4 = reinterpret_cast<const float4*>(refCov + p0 * 53);
    for (int f = tid; f < 3392; f += 256) {
        float4 v = src4[f];
        const int e = f * 4;
        #pragma unroll
        for (int k = 0; k < 4; ++k) {
            const int g = e + k;
            const int row = g / 53;
            const int col = g - row * 53;
            smem[row * 56 + col] = bfbits(((const float*)&v)[k]);
        }
    }
    smem[tid * 56 + 53] = 0;
    smem[tid * 56 + 54] = 0;
    smem[tid * 56 + 55] = 0;
    __syncthreads();

    bf16x8 afr[4][2];
    #pragma unroll
    for (int mi = 0; mi < 4; ++mi) {
        const ushort_t* rp = smem + (w * 64 + mi * 16 + lr) * 56;
        afr[mi][0] = load_frag(rp + quad * 8);
        afr[mi][1] = (quad < 3) ? load_frag(rp + 32 + quad * 8) : zero_frag();
    }
    __syncthreads();

    ushort_t* C1w = smem + w * 2560;   // per-wave [64][40] bf16

    #pragma unroll
    for (int l = 0; l < NLAY; ++l) {
        const float bias0 = br1[l * 32 + lr];
        const float bias1 = br1[l * 32 + 16 + lr];
        const float bias2 = br2[l * 8 + (lr & 7)];
        bf16x8 w1f[2][2];
        #pragma unroll
        for (int ni = 0; ni < 2; ++ni)
            #pragma unroll
            for (int ks = 0; ks < 2; ++ks)
                w1f[ni][ks] = load_frag(W1T + ((l * 32 + ni * 16 + lr) * 64) + ks * 32 + quad * 8);
        bf16x8 w2f = load_frag(W2T + (l * 16 + lr) * 32 + quad * 8);

        f32x4 acc[4][2];
        #pragma unroll
        for (int mi = 0; mi < 4; ++mi) {
            acc[mi][0] = (f32x4){bias0, bias0, bias0, bias0};
            acc[mi][1] = (f32x4){bias1, bias1, bias1, bias1};
        }
        #pragma unroll
        for (int mi = 0; mi < 4; ++mi) {
            acc[mi][0] = mfma16(afr[mi][0], w1f[0][0], acc[mi][0]);
            acc[mi][0] = mfma16(afr[mi][1], w1f[0][1], acc[mi][0]);
            acc[mi][1] = mfma16(afr[mi][0], w1f[1][0], acc[mi][1]);
            acc[mi][1] = mfma16(afr[mi][1], w1f[1][1], acc[mi][1]);
        }
        #pragma unroll
        for (int mi = 0; mi < 4; ++mi)
            #pragma unroll
            for (int ni = 0; ni < 2; ++ni)
                #pragma unroll
                for (int r = 0; r < 4; ++r)
                    C1w[(mi * 16 + quad * 4 + r) * 40 + ni * 16 + lr] =
                        bfbits(fmaxf(acc[mi][ni][r], 0.f));

        #pragma unroll
        for (int mi = 0; mi < 4; ++mi) {
            bf16x8 a2 = load_frag(C1w + (mi * 16 + lr) * 40 + quad * 8);
            f32x4 a = (f32x4){bias2, bias2, bias2, bias2};
            a = mfma16(a2, w2f, a);
            if (lr < 8) {
                uint2 pk;
                pk.x = (unsigned)bfbits(a[0]) | ((unsigned)bfbits(a[1]) << 16);
                pk.y = (unsigned)bfbits(a[2]) | ((unsigned)bfbits(a[3]) << 16);
                const size_t plane = ((size_t)(l * 8 + b) * 8 + lr) * LL2;
                *reinterpret_cast<uint2*>((ushort_t*)refL + plane + rem0 +
                                          w * 64 + mi * 16 + quad * 4) = pk;
            }
        }
    }
}

// ---------------------------------------------------------------------------
// Fused QKV GEMM: [3072,512] @ WTqkv^T[1536] -> q/k/vT. grid 1152 x 256.
__global__ __launch_bounds__(256) void gemm_qkv_kernel(
    const __hip_bfloat16* __restrict__ A,
    const __hip_bfloat16* __restrict__ BT,
    const float* __restrict__ bq, const float* __restrict__ bk,
    const float* __restrict__ bv,
    __hip_bfloat16* __restrict__ q, __hip_bfloat16* __restrict__ kk,
    __hip_bfloat16* __restrict__ vT)
{
    const int bm = blockIdx.x % (BL / 64);
    const int bn = blockIdx.x / (BL / 64);     // 0..23
    const int wv = threadIdx.x >> 6;
    const int lane = threadIdx.x & 63;
    const int lr = lane & 15, quad = lane >> 4;
    const int m0 = bm * 64 + (wv & 1) * 32;
    const int n0g = bn * 64 + (wv >> 1) * 32;  // global n' in [0,1536)
    f32x4 acc[2][2];
    #pragma unroll
    for (int i = 0; i < 2; ++i)
        #pragma unroll
        for (int j = 0; j < 2; ++j) acc[i][j] = (f32x4){0.f, 0.f, 0.f, 0.f};
    const __hip_bfloat16* a0p = A + (size_t)(m0 + lr) * HID;
    const __hip_bfloat16* a1p = A + (size_t)(m0 + 16 + lr) * HID;
    const __hip_bfloat16* b0p = BT + (size_t)(n0g + lr) * HID;
    const __hip_bfloat16* b1p = BT + (size_t)(n0g + 16 + lr) * HID;
    #pragma unroll 4
    for (int k0 = 0; k0 < HID; k0 += 32) {
        const int ka = k0 + quad * 8;
        bf16x8 a0 = load_frag(a0p + ka);
        bf16x8 a1 = load_frag(a1p + ka);
        bf16x8 b0 = load_frag(b0p + ka);
        bf16x8 b1 = load_frag(b1p + ka);
        acc[0][0] = mfma16(a0, b0, acc[0][0]);
        acc[0][1] = mfma16(a0, b1, acc[0][1]);
        acc[1][0] = mfma16(a1, b0, acc[1][0]);
        acc[1][1] = mfma16(a1, b1, acc[1][1]);
    }
    const int mat = n0g >> 9;
    const float* bias = (mat == 0) ? bq : (mat == 1) ? bk : bv;
    const float scale = (mat == 0) ? 0.125f : 1.0f;
    __hip_bfloat16* outp = (mat == 0) ? q : (mat == 1) ? kk : vT;
    #pragma unroll
    for (int mi = 0; mi < 2; ++mi)
        #pragma unroll
        for (int ni = 0; ni < 2; ++ni)
            #pragma unroll
            for (int r = 0; r < 4; ++r) {
                const int m = m0 + mi * 16 + quad * 4 + r;
                const int ng = n0g + ni * 16 + lr;
                const int n = ng & 511;
                float v = (acc[mi][ni][r] + bias[n]) * scale;
                const int bb = m / LSEQ, ii = m % LSEQ;
                const int hh = n >> 6, d = n & 63;
                if (mat == 2)
                    outp[((size_t)(bb * NHEAD + hh) * DKH + d) * LSEQ + ii] = __float2bfloat16(v);
                else
                    outp[((size_t)(bb * NHEAD + hh) * LSEQ + ii) * DKH + d] = __float2bfloat16(v);
            }
}

// ---------------------------------------------------------------------------
// O-projection: proj[3072,512] = AO @ WTo^T + bo (fp32 out). grid 384 x 256.
__global__ __launch_bounds__(256) void gemm_oproj_kernel(
    const __hip_bfloat16* __restrict__ A,
    const __hip_bfloat16* __restrict__ BT,
    const float* __restrict__ bias,
    float* __restrict__ outf)
{
    const int bm = blockIdx.x % (BL / 64);
    const int bn = blockIdx.x / (BL / 64);
    const int wv = threadIdx.x >> 6;
    const int lane = threadIdx.x & 63;
    const int lr = lane & 15, quad = lane >> 4;
    const int m0 = bm * 64 + (wv & 1) * 32;
    const int n0 = bn * 64 + (wv >> 1) * 32;
    f32x4 acc[2][2];
    #pragma unroll
    for (int i = 0; i < 2; ++i)
        #pragma unroll
        for (int j = 0; j < 2; ++j) acc[i][j] = (f32x4){0.f, 0.f, 0.f, 0.f};
    const __hip_bfloat16* a0p = A + (size_t)(m0 + lr) * HID;
    const __hip_bfloat16* a1p = A + (size_t)(m0 + 16 + lr) * HID;
    const __hip_bfloat16* b0p = BT + (size_t)(n0 + lr) * HID;
    const __hip_bfloat16* b1p = BT + (size_t)(n0 + 16 + lr) * HID;
    #pragma unroll 4
    for (int k0 = 0; k0 < HID; k0 += 32) {
        const int ka = k0 + quad * 8;
        bf16x8 a0 = load_frag(a0p + ka);
        bf16x8 a1 = load_frag(a1p + ka);
        bf16x8 b0 = load_frag(b0p + ka);
        bf16x8 b1 = load_frag(b1p + ka);
        acc[0][0] = mfma16(a0, b0, acc[0][0]);
        acc[0][1] = mfma16(a0, b1, acc[0][1]);
        acc[1][0] = mfma16(a1, b0, acc[1][0]);
        acc[1][1] = mfma16(a1, b1, acc[1][1]);
    }
    #pragma unroll
    for (int mi = 0; mi < 2; ++mi)
        #pragma unroll
        for (int ni = 0; ni < 2; ++ni)
            #pragma unroll
            for (int r = 0; r < 4; ++r) {
                const int m = m0 + mi * 16 + quad * 4 + r;
                const int n = n0 + ni * 16 + lr;
                outf[(size_t)m * HID + n] = acc[mi][ni][r] + bias[n];
            }
}

// ---------------------------------------------------------------------------
// Fused attention, 8-wave blocks: wave (s,h4) owns 16 rows x 96 cols of S.
// grid 64 bh x 12 row-tiles = 768 blocks x 512 thr.
__global__ __launch_bounds__(512) void attn_fused_kernel(
    const __hip_bfloat16* __restrict__ Q,    // [bh][i][d]
    const __hip_bfloat16* __restrict__ Km,   // [bh][j][d]
    const __hip_bfloat16* __restrict__ VT,   // [bh][d][j]
    const __hip_bfloat16* __restrict__ refl, // + l*BH*LL2, [bh][i][j]
    const unsigned char* __restrict__ mask,
    __hip_bfloat16* __restrict__ AO)         // [b*384+i][h*64+d]
{
    __shared__ __align__(16) ushort_t Pl[32 * 392];   // P tile, padded rows
    __shared__ float redm_s[2][4][16], redm_r[2][4][16];
    __shared__ float reds_s[2][4][16], reds_r[2][4][16];

    const int bh = blockIdx.x / 12;
    const int i0 = (blockIdx.x % 12) * 32;
    const int b  = bh >> 3, hh = bh & 7;
    const int w = threadIdx.x >> 6, lane = threadIdx.x & 63;
    const int s = w & 1, h4 = w >> 1;              // row strip, col quarter
    const int lr = lane & 15, quad = lane >> 4;

    const __hip_bfloat16* qb = Q  + (size_t)bh * LSEQ * DKH;
    const __hip_bfloat16* kb = Km + (size_t)bh * LSEQ * DKH;
    const unsigned char* mrow = mask + b * LSEQ;

    // ---- S strip: rows [i0+s*16, +16), cols [h4*96, +96) ----
    f32x4 acc[6];
    #pragma unroll
    for (int nt = 0; nt < 6; ++nt) acc[nt] = (f32x4){0.f, 0.f, 0.f, 0.f};
    #pragma unroll
    for (int k0 = 0; k0 < DKH; k0 += 32) {
        const int ka = k0 + quad * 8;
        bf16x8 a = load_frag(qb + (size_t)(i0 + s * 16 + lr) * DKH + ka);
        #pragma unroll
        for (int nt = 0; nt < 6; ++nt) {
            bf16x8 bf = load_frag(kb + (size_t)(h4 * 96 + nt * 16 + lr) * DKH + ka);
            acc[nt] = mfma16(a, bf, acc[nt]);
        }
    }

    bool vm[6];
    #pragma unroll
    for (int nt = 0; nt < 6; ++nt)
        vm[nt] = mrow[h4 * 96 + nt * 16 + lr] != 0;

    const __hip_bfloat16* rbase = refl + (size_t)bh * LL2 +
                                  (size_t)(i0 + s * 16) * LSEQ + h4 * 96;
    float rv[6][4];
    #pragma unroll
    for (int nt = 0; nt < 6; ++nt)
        #pragma unroll
        for (int r = 0; r < 4; ++r)
            rv[nt][r] = b2f(rbase[(size_t)(quad * 4 + r) * LSEQ + nt * 16 + lr]);

    // ---- masked max ----
    float ms[4], mr2[4];
    #pragma unroll
    for (int r = 0; r < 4; ++r) { ms[r] = -1e30f; mr2[r] = -1e30f; }
    #pragma unroll
    for (int nt = 0; nt < 6; ++nt)
        #pragma unroll
        for (int r = 0; r < 4; ++r) {
            acc[nt][r] = vm[nt] ? acc[nt][r] : -1e30f;
            rv[nt][r]  = vm[nt] ? rv[nt][r]  : -1e30f;
            ms[r]  = fmaxf(ms[r],  acc[nt][r]);
            mr2[r] = fmaxf(mr2[r], rv[nt][r]);
        }
    #pragma unroll
    for (int off = 8; off > 0; off >>= 1)
        #pragma unroll
        for (int r = 0; r < 4; ++r) {
            ms[r]  = fmaxf(ms[r],  __shfl_xor(ms[r],  off));
            mr2[r] = fmaxf(mr2[r], __shfl_xor(mr2[r], off));
        }
    if (lr == 0)
        #pragma unroll
        for (int r = 0; r < 4; ++r) {
            redm_s[s][h4][quad * 4 + r] = ms[r];
            redm_r[s][h4][quad * 4 + r] = mr2[r];
        }
    __syncthreads();
    #pragma unroll
    for (int r = 0; r < 4; ++r) {
        const int x = quad * 4 + r;
        ms[r]  = fmaxf(fmaxf(redm_s[s][0][x], redm_s[s][1][x]),
                       fmaxf(redm_s[s][2][x], redm_s[s][3][x]));
        mr2[r] = fmaxf(fmaxf(redm_r[s][0][x], redm_r[s][1][x]),
                       fmaxf(redm_r[s][2][x], redm_r[s][3][x]));
    }

    // ---- exp + sum ----
    float Ss[4] = {0.f, 0.f, 0.f, 0.f}, Sr[4] = {0.f, 0.f, 0.f, 0.f};
    #pragma unroll
    for (int nt = 0; nt < 6; ++nt)
        #pragma unroll
        for (int r = 0; r < 4; ++r) {
            acc[nt][r] = __expf(acc[nt][r] - ms[r]);  Ss[r] += acc[nt][r];
            rv[nt][r]  = __expf(rv[nt][r]  - mr2[r]); Sr[r] += rv[nt][r];
        }
    #pragma unroll
    for (int off = 8; off > 0; off >>= 1)
        #pragma unroll
        for (int r = 0; r < 4; ++r) {
            Ss[r] += __shfl_xor(Ss[r], off);
            Sr[r] += __shfl_xor(Sr[r], off);
        }
    if (lr == 0)
        #pragma unroll
        for (int r = 0; r < 4; ++r) {
            reds_s[s][h4][quad * 4 + r] = Ss[r];
            reds_r[s][h4][quad * 4 + r] = Sr[r];
        }
    __syncthreads();

    // ---- combine -> P (bf16, LDS) ----
    float cs[4], cr[4], rm[4];
    #pragma unroll
    for (int r = 0; r < 4; ++r) {
        const int x = quad * 4 + r;
        const float SsF = reds_s[s][0][x] + reds_s[s][1][x] +
                          reds_s[s][2][x] + reds_s[s][3][x];
        const float SrF = reds_r[s][0][x] + reds_r[s][1][x] +
                          reds_r[s][2][x] + reds_r[s][3][x];
        cs[r] = 0.5f / SsF;
        cr[r] = 0.5f / SrF;
        rm[r] = mrow[i0 + s * 16 + x] ? 1.f : 0.f;
    }
    #pragma unroll
    for (int nt = 0; nt < 6; ++nt)
        #pragma unroll
        for (int r = 0; r < 4; ++r)
            Pl[(s * 16 + quad * 4 + r) * 392 + h4 * 96 + nt * 16 + lr] =
                bfbits((acc[nt][r] * cs[r] + rv[nt][r] * cr[r]) * rm[r]);
    __syncthreads();

    // ---- PV: wave out strip = rows [s*16,+16) x d [h4*16,+16) ----
    const __hip_bfloat16* vb = VT + (size_t)bh * DKH * LSEQ;
    f32x4 oa = (f32x4){0.f, 0.f, 0.f, 0.f};
    #pragma unroll 4
    for (int k0 = 0; k0 < LSEQ; k0 += 32) {
        const int ka = k0 + quad * 8;
        bf16x8 a = load_frag(Pl + (s * 16 + lr) * 392 + ka);
        bf16x8 bf = load_frag(vb + (size_t)(h4 * 16 + lr) * LSEQ + ka);
        oa = mfma16(a, bf, oa);
    }
    #pragma unroll
    for (int r = 0; r < 4; ++r)
        AO[(size_t)(b * LSEQ + i0 + s * 16 + quad * 4 + r) * HID +
           hh * DKH + h4 * 16 + lr] = __float2bfloat16(oa[r]);
}

// ---------------------------------------------------------------------------
// LayerNorm. flags: 1=add proj, 2=zero masked rows, 4=write bf16. grid 3072 x 256
__global__ __launch_bounds__(256) void ln_kernel(
    const float* __restrict__ resid, const float* __restrict__ proj,
    const float* __restrict__ g, const float* __restrict__ beta,
    float* __restrict__ outf, __hip_bfloat16* __restrict__ outb,
    const unsigned char* __restrict__ mask, int flags)
{
    const int row = blockIdx.x, tid = threadIdx.x;
    const size_t base = (size_t)row * HID;
    float x0 = resid[base + tid], x1 = resid[base + tid + 256];
    if (flags & 1) { x0 += proj[base + tid]; x1 += proj[base + tid + 256]; }
    float s = x0 + x1, s2 = x0 * x0 + x1 * x1;
    #pragma unroll
    for (int off = 32; off > 0; off >>= 1) {
        s += __shfl_xor(s, off);
        s2 += __shfl_xor(s2, off);
    }
    __shared__ float rs[4], rs2[4];
    if ((tid & 63) == 0) { rs[tid >> 6] = s; rs2[tid >> 6] = s2; }
    __syncthreads();
    s = rs[0] + rs[1] + rs[2] + rs[3];
    s2 = rs2[0] + rs2[1] + rs2[2] + rs2[3];
    const float mu = s * (1.f / HID);
    const float var = s2 * (1.f / HID) - mu * mu;
    const float rstd = rsqrtf(var + 1e-5f);
    float y0 = (x0 - mu) * rstd * g[tid] + beta[tid];
    float y1 = (x1 - mu) * rstd * g[tid + 256] + beta[tid + 256];
    if ((flags & 2) && !mask[row]) { y0 = 0.f; y1 = 0.f; }
    outf[base + tid] = y0;
    outf[base + tid + 256] = y1;
    if (flags & 4) {
        outb[base + tid] = __float2bfloat16(y0);
        outb[base + tid + 256] = __float2bfloat16(y1);
    }
}

// ---------------------------------------------------------------------------
// final reduce over sequence: out[b][c] = sum_l hfin[b][l][c]. grid 8 x 512
__global__ __launch_bounds__(512) void reduce_kernel(
    const float* __restrict__ hf, float* __restrict__ out)
{
    const int b = blockIdx.x, c = threadIdx.x;
    float s = 0.f;
    for (int i = 0; i < LSEQ; ++i)
        s += hf[((size_t)(b * LSEQ + i)) * HID + c];
    out[b * HID + c] = s;
}

// ---------------------------------------------------------------------------
extern "C" void kernel_launch(void* const* d_in, const int* in_sizes, int n_in,
                              void* d_out, int out_size, void* d_ws, size_t ws_size,
                              hipStream_t stream)
{
    const float* x   = (const float*)d_in[0];
    const unsigned char* mraw = (const unsigned char*)d_in[1];
    const float* refCov = (const float*)d_in[2];
    const float* Wq = (const float*)d_in[3];
    const float* bq = (const float*)d_in[4];
    const float* Wk = (const float*)d_in[5];
    const float* bk = (const float*)d_in[6];
    const float* Wv = (const float*)d_in[7];
    const float* bv = (const float*)d_in[8];
    const float* Wo = (const float*)d_in[9];
    const float* bo = (const float*)d_in[10];
    const float* Wr1 = (const float*)d_in[11];
    const float* br1 = (const float*)d_in[12];
    const float* Wr2 = (const float*)d_in[13];
    const float* br2 = (const float*)d_in[14];
    const float* ln_g = (const float*)d_in[15];
    const float* ln_b = (const float*)d_in[16];
    const float* fn_g = (const float*)d_in[17];
    const float* fn_b = (const float*)d_in[18];
    float* outp = (float*)d_out;

    char* ws = (char*)d_ws;
    size_t off = 0;
    auto alloc = [&](size_t bytes) -> char* {
        char* p = ws + off;
        off += (bytes + 255) & ~(size_t)255;
        return p;
    };
    __hip_bfloat16* refL  = (__hip_bfloat16*)alloc((size_t)NLAY * BH * LL2 * 2);
    float*          h     = (float*)alloc((size_t)BL * HID * 4);
    __hip_bfloat16* hb    = (__hip_bfloat16*)alloc((size_t)BL * HID * 2);
    __hip_bfloat16* q     = (__hip_bfloat16*)alloc((size_t)BH * LSEQ * DKH * 2);
    __hip_bfloat16* kk    = (__hip_bfloat16*)alloc((size_t)BH * LSEQ * DKH * 2);
    __hip_bfloat16* vT    = (__hip_bfloat16*)alloc((size_t)BH * DKH * LSEQ * 2);
    float*          S     = (float*)alloc((size_t)BH * LL2 * 4);   // hfin alias
    __hip_bfloat16* AO    = (__hip_bfloat16*)alloc((size_t)BL * HID * 2);
    float*          proj  = (float*)alloc((size_t)BL * HID * 4);
    ushort_t*       WTqkv = (ushort_t*)alloc((size_t)NLAY * 1536 * HID * 2);
    ushort_t*       WTo   = (ushort_t*)alloc((size_t)NLAY * HID * HID * 2);
    ushort_t*       W1T   = (ushort_t*)alloc((size_t)4 * 32 * 64 * 2);
    ushort_t*       W2T   = (ushort_t*)alloc((size_t)4 * 16 * 32 * 2);
    unsigned char*  msk   = (unsigned char*)alloc(BL);
    float*          hfin  = S;

    mask_norm_kernel<<<1, 1024, 0, stream>>>(mraw, msk);
    wconv_kernel<<<4096, 256, 0, stream>>>(Wq, Wk, Wv, Wo, WTqkv, WTo);
    refw_kernel<<<40, 256, 0, stream>>>(Wr1, Wr2, W1T, W2T);
    pack_kernel<<<6144, 256, 0, stream>>>(x, msk, h, hb);
    refmlp_kernel<<<4608, 256, 0, stream>>>(refCov, W1T, br1, W2T, br2, refL);

    for (int l = 0; l < NLAY; ++l) {
        const __hip_bfloat16* WTl = (const __hip_bfloat16*)(WTqkv + (size_t)l * 1536 * HID);
        const __hip_bfloat16* WTol = (const __hip_bfloat16*)(WTo + (size_t)l * HID * HID);
        gemm_qkv_kernel<<<1152, 256, 0, stream>>>(hb, WTl, bq + l * HID, bk + l * HID,
                                                  bv + l * HID, q, kk, vT);
        attn_fused_kernel<<<768, 512, 0, stream>>>(q, kk, vT,
                                                   refL + (size_t)l * BH * LL2, msk, AO);
        gemm_oproj_kernel<<<384, 256, 0, stream>>>(AO, WTol, bo + l * HID, proj);
        ln_kernel<<<3072, 256, 0, stream>>>(h, proj, ln_g + l * HID, ln_b + l * HID,
                                            h, hb, nullptr, 1 | 4);
    }
    ln_kernel<<<3072, 256, 0, stream>>>(h, nullptr, fn_g, fn_b, hfin, nullptr, msk, 2);
    reduce_kernel<<<8, 512, 0, stream>>>(hfin, outp);
}

// Round 6
// 805.537 us; speedup vs baseline: 1.0799x; 1.0304x over previous
//
#include <hip/hip_runtime.h>
#include <hip/hip_bf16.h>
#include <cstdint>

constexpr int LSEQ  = 384;
constexpr int BATCH = 8;
constexpr int HID   = 512;
constexpr int NHEAD = 8;
constexpr int DKH   = 64;
constexpr int NLAY  = 4;
constexpr int BL    = BATCH * LSEQ;      // 3072 rows
constexpr int LL2   = LSEQ * LSEQ;       // 147456 pairs per batch
constexpr int BH    = BATCH * NHEAD;     // 64

typedef __bf16 bf16x8 __attribute__((ext_vector_type(8)));
typedef float  f32x4  __attribute__((ext_vector_type(4)));
typedef unsigned short ushort_t;

__device__ inline bf16x8 load_frag(const void* p) {
    uint4 u = *reinterpret_cast<const uint4*>(p);
    return __builtin_bit_cast(bf16x8, u);
}
__device__ inline bf16x8 zero_frag() {
    uint4 u = {0u, 0u, 0u, 0u};
    return __builtin_bit_cast(bf16x8, u);
}
__device__ inline f32x4 mfma16(bf16x8 a, bf16x8 b, f32x4 c) {
    return __builtin_amdgcn_mfma_f32_16x16x32_bf16(a, b, c, 0, 0, 0);
}
__device__ inline float b2f(__hip_bfloat16 v) { return __bfloat162float(v); }
__device__ inline ushort_t bfbits(float f) {
    __hip_bfloat16 b = __float2bfloat16(f);
    return *(ushort_t*)&b;
}

// ---------------------------------------------------------------------------
// Normalize mask storage (u8 / i32 / i64 / bf16 / f32 bools) -> uchar[3072].
__global__ __launch_bounds__(1024) void mask_norm_kernel(
    const unsigned char* __restrict__ raw, unsigned char* __restrict__ m)
{
    __shared__ int fl;
    const int tid = threadIdx.x;
    if (tid == 0) fl = 0;
    __syncthreads();
    int f = 0;
    for (int i = tid; i < BL; i += 1024) {
        const unsigned char v = raw[i];
        if (v > 1) f |= 1;
        if (v && (i & 3)) f |= 2;
        if (v && ((i & 7) == 4)) f |= 4;
        if (v && ((i & 3) <= 1)) f |= 8;
    }
    if (f) atomicOr(&fl, f);
    __syncthreads();
    const int ff = fl;
    int stride, off;
    if (ff & 1) { if (ff & 8) { stride = 2; off = 0; } else { stride = 4; off = 2; } }
    else if (ff & 2) { stride = 1; off = 0; }
    else if (ff & 4) { stride = 4; off = 0; }
    else             { stride = 8; off = 0; }
    for (int i = tid; i < BL; i += 1024)
        m[i] = raw[(size_t)i * stride + off] ? 1 : 0;
}

// ---------------------------------------------------------------------------
// Weight convert+transpose: fp32 -> bf16, MFMA B-layout.
__global__ __launch_bounds__(256) void wconv_kernel(
    const float* __restrict__ Wq, const float* __restrict__ Wk,
    const float* __restrict__ Wv, const float* __restrict__ Wo,
    ushort_t* __restrict__ WTqkv, ushort_t* __restrict__ WTo)
{
    __shared__ float tile[32][33];
    const int t = blockIdx.x;
    const int ml = t >> 8;            // mat*4 + layer
    const int rest = t & 255;
    const int mi = ml >> 2, l = ml & 3;
    const int tk = (rest & 15) * 32;
    const int tn = (rest >> 4) * 32;
    const float* W = (mi == 0) ? Wq : (mi == 1) ? Wk : (mi == 2) ? Wv : Wo;
    const float* src = W + (size_t)l * HID * HID;
    const int c = threadIdx.x & 31, r = threadIdx.x >> 5;
    for (int rr = r; rr < 32; rr += 8)
        tile[rr][c] = src[(size_t)(tk + rr) * HID + tn + c];
    __syncthreads();
    ushort_t* dst = (mi < 3)
        ? WTqkv + ((size_t)l * 1536 + mi * 512) * HID
        : WTo   + (size_t)l * HID * HID;
    for (int rr = r; rr < 32; rr += 8)
        dst[(size_t)(tn + rr) * HID + tk + c] = bfbits(tile[c][rr]);
}

// ---------------------------------------------------------------------------
// refCov-MLP weights -> bf16 MFMA B-layout in global.
__global__ __launch_bounds__(256) void refw_kernel(
    const float* __restrict__ Wr1, const float* __restrict__ Wr2,
    ushort_t* __restrict__ W1T, ushort_t* __restrict__ W2T)
{
    const int tid = blockIdx.x * 256 + threadIdx.x;
    if (tid < 4 * 32 * 64) {
        const int l = tid >> 11, rem = tid & 2047;
        const int n = rem >> 6, k = rem & 63;
        W1T[tid] = (k < 53) ? bfbits(Wr1[(l * 53 + k) * 32 + n]) : (ushort_t)0;
    } else if (tid < 4 * 32 * 64 + 4 * 16 * 32) {
        const int t2 = tid - 8192;
        const int l = t2 >> 9, rem = t2 & 511;
        const int n = rem >> 5, k = rem & 31;
        W2T[t2] = (n < 8) ? bfbits(Wr2[(l * 32 + k) * 8 + n]) : (ushort_t)0;
    }
}

// ---------------------------------------------------------------------------
// pack: h = x * mask (fp32 + bf16 copies). grid 6144 x 256
__global__ __launch_bounds__(256) void pack_kernel(
    const float* __restrict__ x, const unsigned char* __restrict__ mask,
    float* __restrict__ h, __hip_bfloat16* __restrict__ hb)
{
    const int idx = blockIdx.x * 256 + threadIdx.x;
    const int row = idx >> 9;
    const float v = mask[row] ? x[idx] : 0.f;
    h[idx] = v;
    hb[idx] = __float2bfloat16(v);
}

// ---------------------------------------------------------------------------
// refCov MLP: 256 pairs/block, A-frags register-resident. grid 4608 x 256.
// Staging batched: all 13(+1) float4 loads issued back-to-back for MLP,
// then scalar-expanded to LDS (was 1 load in flight -> latency-bound, m154us).
__global__ __launch_bounds__(256) void refmlp_kernel(
    const float* __restrict__ refCov,
    const ushort_t* __restrict__ W1T, const float* __restrict__ br1,
    const ushort_t* __restrict__ W2T, const float* __restrict__ br2,
    __hip_bfloat16* __restrict__ refL)
{
    __shared__ ushort_t smem[256 * 56];   // 28672 B: Atile, later C1 overlay

    const int tid = threadIdx.x;
    const int w = tid >> 6, lane = tid & 63;
    const int lr = lane & 15, quad = lane >> 4;
    const size_t p0 = (size_t)blockIdx.x * 256;
    const int b = (int)(p0 / LL2);
    const int rem0 = (int)(p0 - (size_t)b * LL2);

    // ---- stage refCov block -> Atile[256][56] bf16, ILP-batched ----
    const float4* src4 = reinterpret_cast<const float4*>(refCov + p0 * 53);
    float4 vb[13];
    #pragma unroll
    for (int i = 0; i < 13; ++i) vb[i] = src4[tid + i * 256];
    float4 vtail;
    if (tid < 64) vtail = src4[tid + 13 * 256];
    #pragma unroll
    for (int i = 0; i < 13; ++i) {
        const int e = (tid + i * 256) * 4;
        #pragma unroll
        for (int k = 0; k < 4; ++k) {
            const int g = e + k;
            const int row = g / 53;
            const int col = g - row * 53;
            smem[row * 56 + col] = bfbits(((const float*)&vb[i])[k]);
        }
    }
    if (tid < 64) {
        const int e = (tid + 13 * 256) * 4;
        #pragma unroll
        for (int k = 0; k < 4; ++k) {
            const int g = e + k;
            const int row = g / 53;
            const int col = g - row * 53;
            smem[row * 56 + col] = bfbits(((const float*)&vtail)[k]);
        }
    }
    smem[tid * 56 + 53] = 0;
    smem[tid * 56 + 54] = 0;
    smem[tid * 56 + 55] = 0;
    __syncthreads();

    bf16x8 afr[4][2];
    #pragma unroll
    for (int mi = 0; mi < 4; ++mi) {
        const ushort_t* rp = smem + (w * 64 + mi * 16 + lr) * 56;
        afr[mi][0] = load_frag(rp + quad * 8);
        afr[mi][1] = (quad < 3) ? load_frag(rp + 32 + quad * 8) : zero_frag();
    }
    __syncthreads();

    ushort_t* C1w = smem + w * 2560;   // per-wave [64][40] bf16

    #pragma unroll
    for (int l = 0; l < NLAY; ++l) {
        const float bias0 = br1[l * 32 + lr];
        const float bias1 = br1[l * 32 + 16 + lr];
        const float bias2 = br2[l * 8 + (lr & 7)];
        bf16x8 w1f[2][2];
        #pragma unroll
        for (int ni = 0; ni < 2; ++ni)
            #pragma unroll
            for (int ks = 0; ks < 2; ++ks)
                w1f[ni][ks] = load_frag(W1T + ((l * 32 + ni * 16 + lr) * 64) + ks * 32 + quad * 8);
        bf16x8 w2f = load_frag(W2T + (l * 16 + lr) * 32 + quad * 8);

        f32x4 acc[4][2];
        #pragma unroll
        for (int mi = 0; mi < 4; ++mi) {
            acc[mi][0] = (f32x4){bias0, bias0, bias0, bias0};
            acc[mi][1] = (f32x4){bias1, bias1, bias1, bias1};
        }
        #pragma unroll
        for (int mi = 0; mi < 4; ++mi) {
            acc[mi][0] = mfma16(afr[mi][0], w1f[0][0], acc[mi][0]);
            acc[mi][0] = mfma16(afr[mi][1], w1f[0][1], acc[mi][0]);
            acc[mi][1] = mfma16(afr[mi][0], w1f[1][0], acc[mi][1]);
            acc[mi][1] = mfma16(afr[mi][1], w1f[1][1], acc[mi][1]);
        }
        #pragma unroll
        for (int mi = 0; mi < 4; ++mi)
            #pragma unroll
            for (int ni = 0; ni < 2; ++ni)
                #pragma unroll
                for (int r = 0; r < 4; ++r)
                    C1w[(mi * 16 + quad * 4 + r) * 40 + ni * 16 + lr] =
                        bfbits(fmaxf(acc[mi][ni][r], 0.f));

        #pragma unroll
        for (int mi = 0; mi < 4; ++mi) {
            bf16x8 a2 = load_frag(C1w + (mi * 16 + lr) * 40 + quad * 8);
            f32x4 a = (f32x4){bias2, bias2, bias2, bias2};
            a = mfma16(a2, w2f, a);
            if (lr < 8) {
                uint2 pk;
                pk.x = (unsigned)bfbits(a[0]) | ((unsigned)bfbits(a[1]) << 16);
                pk.y = (unsigned)bfbits(a[2]) | ((unsigned)bfbits(a[3]) << 16);
                const size_t plane = ((size_t)(l * 8 + b) * 8 + lr) * LL2;
                *reinterpret_cast<uint2*>((ushort_t*)refL + plane + rem0 +
                                          w * 64 + mi * 16 + quad * 4) = pk;
            }
        }
    }
}

// ---------------------------------------------------------------------------
// Fused QKV GEMM: [3072,512] @ WTqkv^T[1536] -> q/k/vT. grid 1152 x 256.
__global__ __launch_bounds__(256) void gemm_qkv_kernel(
    const __hip_bfloat16* __restrict__ A,
    const __hip_bfloat16* __restrict__ BT,
    const float* __restrict__ bq, const float* __restrict__ bk,
    const float* __restrict__ bv,
    __hip_bfloat16* __restrict__ q, __hip_bfloat16* __restrict__ kk,
    __hip_bfloat16* __restrict__ vT)
{
    const int bm = blockIdx.x % (BL / 64);
    const int bn = blockIdx.x / (BL / 64);     // 0..23
    const int wv = threadIdx.x >> 6;
    const int lane = threadIdx.x & 63;
    const int lr = lane & 15, quad = lane >> 4;
    const int m0 = bm * 64 + (wv & 1) * 32;
    const int n0g = bn * 64 + (wv >> 1) * 32;  // global n' in [0,1536)
    f32x4 acc[2][2];
    #pragma unroll
    for (int i = 0; i < 2; ++i)
        #pragma unroll
        for (int j = 0; j < 2; ++j) acc[i][j] = (f32x4){0.f, 0.f, 0.f, 0.f};
    const __hip_bfloat16* a0p = A + (size_t)(m0 + lr) * HID;
    const __hip_bfloat16* a1p = A + (size_t)(m0 + 16 + lr) * HID;
    const __hip_bfloat16* b0p = BT + (size_t)(n0g + lr) * HID;
    const __hip_bfloat16* b1p = BT + (size_t)(n0g + 16 + lr) * HID;
    #pragma unroll 4
    for (int k0 = 0; k0 < HID; k0 += 32) {
        const int ka = k0 + quad * 8;
        bf16x8 a0 = load_frag(a0p + ka);
        bf16x8 a1 = load_frag(a1p + ka);
        bf16x8 b0 = load_frag(b0p + ka);
        bf16x8 b1 = load_frag(b1p + ka);
        acc[0][0] = mfma16(a0, b0, acc[0][0]);
        acc[0][1] = mfma16(a0, b1, acc[0][1]);
        acc[1][0] = mfma16(a1, b0, acc[1][0]);
        acc[1][1] = mfma16(a1, b1, acc[1][1]);
    }
    const int mat = n0g >> 9;
    const float* bias = (mat == 0) ? bq : (mat == 1) ? bk : bv;
    const float scale = (mat == 0) ? 0.125f : 1.0f;
    __hip_bfloat16* outp = (mat == 0) ? q : (mat == 1) ? kk : vT;
    #pragma unroll
    for (int mi = 0; mi < 2; ++mi)
        #pragma unroll
        for (int ni = 0; ni < 2; ++ni)
            #pragma unroll
            for (int r = 0; r < 4; ++r) {
                const int m = m0 + mi * 16 + quad * 4 + r;
                const int ng = n0g + ni * 16 + lr;
                const int n = ng & 511;
                float v = (acc[mi][ni][r] + bias[n]) * scale;
                const int bb = m / LSEQ, ii = m % LSEQ;
                const int hh = n >> 6, d = n & 63;
                if (mat == 2)
                    outp[((size_t)(bb * NHEAD + hh) * DKH + d) * LSEQ + ii] = __float2bfloat16(v);
                else
                    outp[((size_t)(bb * NHEAD + hh) * LSEQ + ii) * DKH + d] = __float2bfloat16(v);
            }
}

// ---------------------------------------------------------------------------
// O-projection: proj[3072,512] = AO @ WTo^T + bo (fp32 out). grid 384 x 256.
__global__ __launch_bounds__(256) void gemm_oproj_kernel(
    const __hip_bfloat16* __restrict__ A,
    const __hip_bfloat16* __restrict__ BT,
    const float* __restrict__ bias,
    float* __restrict__ outf)
{
    const int bm = blockIdx.x % (BL / 64);
    const int bn = blockIdx.x / (BL / 64);
    const int wv = threadIdx.x >> 6;
    const int lane = threadIdx.x & 63;
    const int lr = lane & 15, quad = lane >> 4;
    const int m0 = bm * 64 + (wv & 1) * 32;
    const int n0 = bn * 64 + (wv >> 1) * 32;
    f32x4 acc[2][2];
    #pragma unroll
    for (int i = 0; i < 2; ++i)
        #pragma unroll
        for (int j = 0; j < 2; ++j) acc[i][j] = (f32x4){0.f, 0.f, 0.f, 0.f};
    const __hip_bfloat16* a0p = A + (size_t)(m0 + lr) * HID;
    const __hip_bfloat16* a1p = A + (size_t)(m0 + 16 + lr) * HID;
    const __hip_bfloat16* b0p = BT + (size_t)(n0 + lr) * HID;
    const __hip_bfloat16* b1p = BT + (size_t)(n0 + 16 + lr) * HID;
    #pragma unroll 4
    for (int k0 = 0; k0 < HID; k0 += 32) {
        const int ka = k0 + quad * 8;
        bf16x8 a0 = load_frag(a0p + ka);
        bf16x8 a1 = load_frag(a1p + ka);
        bf16x8 b0 = load_frag(b0p + ka);
        bf16x8 b1 = load_frag(b1p + ka);
        acc[0][0] = mfma16(a0, b0, acc[0][0]);
        acc[0][1] = mfma16(a0, b1, acc[0][1]);
        acc[1][0] = mfma16(a1, b0, acc[1][0]);
        acc[1][1] = mfma16(a1, b1, acc[1][1]);
    }
    #pragma unroll
    for (int mi = 0; mi < 2; ++mi)
        #pragma unroll
        for (int ni = 0; ni < 2; ++ni)
            #pragma unroll
            for (int r = 0; r < 4; ++r) {
                const int m = m0 + mi * 16 + quad * 4 + r;
                const int n = n0 + ni * 16 + lr;
                outf[(size_t)m * HID + n] = acc[mi][ni][r] + bias[n];
            }
}

// ---------------------------------------------------------------------------
// Fused attention, 8-wave blocks: wave (s,h4) owns 16 rows x 96 cols of S.
// grid 64 bh x 12 row-tiles = 768 blocks x 512 thr.
__global__ __launch_bounds__(512) void attn_fused_kernel(
    const __hip_bfloat16* __restrict__ Q,    // [bh][i][d]
    const __hip_bfloat16* __restrict__ Km,   // [bh][j][d]
    const __hip_bfloat16* __restrict__ VT,   // [bh][d][j]
    const __hip_bfloat16* __restrict__ refl, // + l*BH*LL2, [bh][i][j]
    const unsigned char* __restrict__ mask,
    __hip_bfloat16* __restrict__ AO)         // [b*384+i][h*64+d]
{
    __shared__ __align__(16) ushort_t Pl[32 * 392];   // P tile, padded rows
    __shared__ float redm_s[2][4][16], redm_r[2][4][16];
    __shared__ float reds_s[2][4][16], reds_r[2][4][16];

    const int bh = blockIdx.x / 12;
    const int i0 = (blockIdx.x % 12) * 32;
    const int b  = bh >> 3, hh = bh & 7;
    const int w = threadIdx.x >> 6, lane = threadIdx.x & 63;
    const int s = w & 1, h4 = w >> 1;              // row strip, col quarter
    const int lr = lane & 15, quad = lane >> 4;

    const __hip_bfloat16* qb = Q  + (size_t)bh * LSEQ * DKH;
    const __hip_bfloat16* kb = Km + (size_t)bh * LSEQ * DKH;
    const unsigned char* mrow = mask + b * LSEQ;

    // ---- S strip: rows [i0+s*16, +16), cols [h4*96, +96) ----
    f32x4 acc[6];
    #pragma unroll
    for (int nt = 0; nt < 6; ++nt) acc[nt] = (f32x4){0.f, 0.f, 0.f, 0.f};
    #pragma unroll
    for (int k0 = 0; k0 < DKH; k0 += 32) {
        const int ka = k0 + quad * 8;
        bf16x8 a = load_frag(qb + (size_t)(i0 + s * 16 + lr) * DKH + ka);
        #pragma unroll
        for (int nt = 0; nt < 6; ++nt) {
            bf16x8 bf = load_frag(kb + (size_t)(h4 * 96 + nt * 16 + lr) * DKH + ka);
            acc[nt] = mfma16(a, bf, acc[nt]);
        }
    }

    bool vm[6];
    #pragma unroll
    for (int nt = 0; nt < 6; ++nt)
        vm[nt] = mrow[h4 * 96 + nt * 16 + lr] != 0;

    const __hip_bfloat16* rbase = refl + (size_t)bh * LL2 +
                                  (size_t)(i0 + s * 16) * LSEQ + h4 * 96;
    float rv[6][4];
    #pragma unroll
    for (int nt = 0; nt < 6; ++nt)
        #pragma unroll
        for (int r = 0; r < 4; ++r)
            rv[nt][r] = b2f(rbase[(size_t)(quad * 4 + r) * LSEQ + nt * 16 + lr]);

    // ---- masked max ----
    float ms[4], mr2[4];
    #pragma unroll
    for (int r = 0; r < 4; ++r) { ms[r] = -1e30f; mr2[r] = -1e30f; }
    #pragma unroll
    for (int nt = 0; nt < 6; ++nt)
        #pragma unroll
        for (int r = 0; r < 4; ++r) {
            acc[nt][r] = vm[nt] ? acc[nt][r] : -1e30f;
            rv[nt][r]  = vm[nt] ? rv[nt][r]  : -1e30f;
            ms[r]  = fmaxf(ms[r],  acc[nt][r]);
            mr2[r] = fmaxf(mr2[r], rv[nt][r]);
        }
    #pragma unroll
    for (int off = 8; off > 0; off >>= 1)
        #pragma unroll
        for (int r = 0; r < 4; ++r) {
            ms[r]  = fmaxf(ms[r],  __shfl_xor(ms[r],  off));
            mr2[r] = fmaxf(mr2[r], __shfl_xor(mr2[r], off));
        }
    if (lr == 0)
        #pragma unroll
        for (int r = 0; r < 4; ++r) {
            redm_s[s][h4][quad * 4 + r] = ms[r];
            redm_r[s][h4][quad * 4 + r] = mr2[r];
        }
    __syncthreads();
    #pragma unroll
    for (int r = 0; r < 4; ++r) {
        const int x = quad * 4 + r;
        ms[r]  = fmaxf(fmaxf(redm_s[s][0][x], redm_s[s][1][x]),
                       fmaxf(redm_s[s][2][x], redm_s[s][3][x]));
        mr2[r] = fmaxf(fmaxf(redm_r[s][0][x], redm_r[s][1][x]),
                       fmaxf(redm_r[s][2][x], redm_r[s][3][x]));
    }

    // ---- exp + sum ----
    float Ss[4] = {0.f, 0.f, 0.f, 0.f}, Sr[4] = {0.f, 0.f, 0.f, 0.f};
    #pragma unroll
    for (int nt = 0; nt < 6; ++nt)
        #pragma unroll
        for (int r = 0; r < 4; ++r) {
            acc[nt][r] = __expf(acc[nt][r] - ms[r]);  Ss[r] += acc[nt][r];
            rv[nt][r]  = __expf(rv[nt][r]  - mr2[r]); Sr[r] += rv[nt][r];
        }
    #pragma unroll
    for (int off = 8; off > 0; off >>= 1)
        #pragma unroll
        for (int r = 0; r < 4; ++r) {
            Ss[r] += __shfl_xor(Ss[r], off);
            Sr[r] += __shfl_xor(Sr[r], off);
        }
    if (lr == 0)
        #pragma unroll
        for (int r = 0; r < 4; ++r) {
            reds_s[s][h4][quad * 4 + r] = Ss[r];
            reds_r[s][h4][quad * 4 + r] = Sr[r];
        }
    __syncthreads();

    // ---- combine -> P (bf16, LDS) ----
    float cs[4], cr[4], rm[4];
    #pragma unroll
    for (int r = 0; r < 4; ++r) {
        const int x = quad * 4 + r;
        const float SsF = reds_s[s][0][x] + reds_s[s][1][x] +
                          reds_s[s][2][x] + reds_s[s][3][x];
        const float SrF = reds_r[s][0][x] + reds_r[s][1][x] +
                          reds_r[s][2][x] + reds_r[s][3][x];
        cs[r] = 0.5f / SsF;
        cr[r] = 0.5f / SrF;
        rm[r] = mrow[i0 + s * 16 + x] ? 1.f : 0.f;
    }
    #pragma unroll
    for (int nt = 0; nt < 6; ++nt)
        #pragma unroll
        for (int r = 0; r < 4; ++r)
            Pl[(s * 16 + quad * 4 + r) * 392 + h4 * 96 + nt * 16 + lr] =
                bfbits((acc[nt][r] * cs[r] + rv[nt][r] * cr[r]) * rm[r]);
    __syncthreads();

    // ---- PV: wave out strip = rows [s*16,+16) x d [h4*16,+16) ----
    const __hip_bfloat16* vb = VT + (size_t)bh * DKH * LSEQ;
    f32x4 oa = (f32x4){0.f, 0.f, 0.f, 0.f};
    #pragma unroll 4
    for (int k0 = 0; k0 < LSEQ; k0 += 32) {
        const int ka = k0 + quad * 8;
        bf16x8 a = load_frag(Pl + (s * 16 + lr) * 392 + ka);
        bf16x8 bf = load_frag(vb + (size_t)(h4 * 16 + lr) * LSEQ + ka);
        oa = mfma16(a, bf, oa);
    }
    #pragma unroll
    for (int r = 0; r < 4; ++r)
        AO[(size_t)(b * LSEQ + i0 + s * 16 + quad * 4 + r) * HID +
           hh * DKH + h4 * 16 + lr] = __float2bfloat16(oa[r]);
}

// ---------------------------------------------------------------------------
// LayerNorm. flags: 1=add proj, 2=zero masked rows, 4=write bf16. grid 3072 x 256
__global__ __launch_bounds__(256) void ln_kernel(
    const float* __restrict__ resid, const float* __restrict__ proj,
    const float* __restrict__ g, const float* __restrict__ beta,
    float* __restrict__ outf, __hip_bfloat16* __restrict__ outb,
    const unsigned char* __restrict__ mask, int flags)
{
    const int row = blockIdx.x, tid = threadIdx.x;
    const size_t base = (size_t)row * HID;
    float x0 = resid[base + tid], x1 = resid[base + tid + 256];
    if (flags & 1) { x0 += proj[base + tid]; x1 += proj[base + tid + 256]; }
    float s = x0 + x1, s2 = x0 * x0 + x1 * x1;
    #pragma unroll
    for (int off = 32; off > 0; off >>= 1) {
        s += __shfl_xor(s, off);
        s2 += __shfl_xor(s2, off);
    }
    __shared__ float rs[4], rs2[4];
    if ((tid & 63) == 0) { rs[tid >> 6] = s; rs2[tid >> 6] = s2; }
    __syncthreads();
    s = rs[0] + rs[1] + rs[2] + rs[3];
    s2 = rs2[0] + rs2[1] + rs2[2] + rs2[3];
    const float mu = s * (1.f / HID);
    const float var = s2 * (1.f / HID) - mu * mu;
    const float rstd = rsqrtf(var + 1e-5f);
    float y0 = (x0 - mu) * rstd * g[tid] + beta[tid];
    float y1 = (x1 - mu) * rstd * g[tid + 256] + beta[tid + 256];
    if ((flags & 2) && !mask[row]) { y0 = 0.f; y1 = 0.f; }
    outf[base + tid] = y0;
    outf[base + tid + 256] = y1;
    if (flags & 4) {
        outb[base + tid] = __float2bfloat16(y0);
        outb[base + tid + 256] = __float2bfloat16(y1);
    }
}

// ---------------------------------------------------------------------------
// final reduce over sequence: out[b][c] = sum_l hfin[b][l][c]. grid 8 x 512
__global__ __launch_bounds__(512) void reduce_kernel(
    const float* __restrict__ hf, float* __restrict__ out)
{
    const int b = blockIdx.x, c = threadIdx.x;
    float s = 0.f;
    for (int i = 0; i < LSEQ; ++i)
        s += hf[((size_t)(b * LSEQ + i)) * HID + c];
    out[b * HID + c] = s;
}

// ---------------------------------------------------------------------------
extern "C" void kernel_launch(void* const* d_in, const int* in_sizes, int n_in,
                              void* d_out, int out_size, void* d_ws, size_t ws_size,
                              hipStream_t stream)
{
    const float* x   = (const float*)d_in[0];
    const unsigned char* mraw = (const unsigned char*)d_in[1];
    const float* refCov = (const float*)d_in[2];
    const float* Wq = (const float*)d_in[3];
    const float* bq = (const float*)d_in[4];
    const float* Wk = (const float*)d_in[5];
    const float* bk = (const float*)d_in[6];
    const float* Wv = (const float*)d_in[7];
    const float* bv = (const float*)d_in[8];
    const float* Wo = (const float*)d_in[9];
    const float* bo = (const float*)d_in[10];
    const float* Wr1 = (const float*)d_in[11];
    const float* br1 = (const float*)d_in[12];
    const float* Wr2 = (const float*)d_in[13];
    const float* br2 = (const float*)d_in[14];
    const float* ln_g = (const float*)d_in[15];
    const float* ln_b = (const float*)d_in[16];
    const float* fn_g = (const float*)d_in[17];
    const float* fn_b = (const float*)d_in[18];
    float* outp = (float*)d_out;

    char* ws = (char*)d_ws;
    size_t off = 0;
    auto alloc = [&](size_t bytes) -> char* {
        char* p = ws + off;
        off += (bytes + 255) & ~(size_t)255;
        return p;
    };
    __hip_bfloat16* refL  = (__hip_bfloat16*)alloc((size_t)NLAY * BH * LL2 * 2);
    float*          h     = (float*)alloc((size_t)BL * HID * 4);
    __hip_bfloat16* hb    = (__hip_bfloat16*)alloc((size_t)BL * HID * 2);
    __hip_bfloat16* q     = (__hip_bfloat16*)alloc((size_t)BH * LSEQ * DKH * 2);
    __hip_bfloat16* kk    = (__hip_bfloat16*)alloc((size_t)BH * LSEQ * DKH * 2);
    __hip_bfloat16* vT    = (__hip_bfloat16*)alloc((size_t)BH * DKH * LSEQ * 2);
    float*          S     = (float*)alloc((size_t)BH * LL2 * 4);   // hfin alias
    __hip_bfloat16* AO    = (__hip_bfloat16*)alloc((size_t)BL * HID * 2);
    float*          proj  = (float*)alloc((size_t)BL * HID * 4);
    ushort_t*       WTqkv = (ushort_t*)alloc((size_t)NLAY * 1536 * HID * 2);
    ushort_t*       WTo   = (ushort_t*)alloc((size_t)NLAY * HID * HID * 2);
    ushort_t*       W1T   = (ushort_t*)alloc((size_t)4 * 32 * 64 * 2);
    ushort_t*       W2T   = (ushort_t*)alloc((size_t)4 * 16 * 32 * 2);
    unsigned char*  msk   = (unsigned char*)alloc(BL);
    float*          hfin  = S;

    mask_norm_kernel<<<1, 1024, 0, stream>>>(mraw, msk);
    wconv_kernel<<<4096, 256, 0, stream>>>(Wq, Wk, Wv, Wo, WTqkv, WTo);
    refw_kernel<<<40, 256, 0, stream>>>(Wr1, Wr2, W1T, W2T);
    pack_kernel<<<6144, 256, 0, stream>>>(x, msk, h, hb);
    refmlp_kernel<<<4608, 256, 0, stream>>>(refCov, W1T, br1, W2T, br2, refL);

    for (int l = 0; l < NLAY; ++l) {
        const __hip_bfloat16* WTl = (const __hip_bfloat16*)(WTqkv + (size_t)l * 1536 * HID);
        const __hip_bfloat16* WTol = (const __hip_bfloat16*)(WTo + (size_t)l * HID * HID);
        gemm_qkv_kernel<<<1152, 256, 0, stream>>>(hb, WTl, bq + l * HID, bk + l * HID,
                                                  bv + l * HID, q, kk, vT);
        attn_fused_kernel<<<768, 512, 0, stream>>>(q, kk, vT,
                                                   refL + (size_t)l * BH * LL2, msk, AO);
        gemm_oproj_kernel<<<384, 256, 0, stream>>>(AO, WTol, bo + l * HID, proj);
        ln_kernel<<<3072, 256, 0, stream>>>(h, proj, ln_g + l * HID, ln_b + l * HID,
                                            h, hb, nullptr, 1 | 4);
    }
    ln_kernel<<<3072, 256, 0, stream>>>(h, nullptr, fn_g, fn_b, hfin, nullptr, msk, 2);
    reduce_kernel<<<8, 512, 0, stream>>>(hfin, outp);
}